// Round 1
// baseline (394.119 us; speedup 1.0000x reference)
//
#include <hip/hip_runtime.h>
#include <hip/hip_bf16.h>

// 3-layer tanh RNN. B=32, T=64, D_IN=10000, H=200, N_CLASSES=2.
//
// R8:
//  * gemm: BM 128->64 so LDS = 68 KB -> 2 blocks/CU (was 86 KB -> 1/CU;
//    counters showed MfmaUtil 18% / VALUBusy 11% / Occ 19% = latency-bound
//    barrier drain with nothing co-resident). Wave split 2M x 4N groups
//    (was 4M x 2N): per-block LDS fragment broadcast traffic 120->84 KB/kstep.
//    One barrier/kstep pipeline otherwise unchanged.
//  * rec: one barrier/step (was two). k-split 10->8 (pow2) with 28-padded
//    k-slices; reduction via 3-step __shfl_xor butterfly in 8-lane groups
//    (part[] LDS round-trip eliminated); h parity double-buffered h[2][224]
//    so the single barrier covers both RAW and WAR. Slice stride 28 floats
//    = conflict-free bank pattern.
//  * split-bf16 3-term everywhere: ~fp32 accuracy at bf16 MFMA rate.

typedef __bf16  bf16x8 __attribute__((ext_vector_type(8)));
typedef __bf16  bf16x4 __attribute__((ext_vector_type(4)));
typedef float   f32x4  __attribute__((ext_vector_type(4)));

#define HDIM 200
#define BM 64
#define CHUNK_B 26624   // bytes per packed k-chunk: [208x32] hi (13312) + lo
#define MFMA(a, b, c) __builtin_amdgcn_mfma_f32_16x16x32_bf16(a, b, c, 0, 0, 0)

__device__ __forceinline__ void glds16(const void* g, void* l) {
    __builtin_amdgcn_global_load_lds(
        (const __attribute__((address_space(1))) unsigned int*)g,
        (__attribute__((address_space(3))) unsigned int*)l, 16, 0, 0);
}

// ---- pack W [HDIM x K] fp32 -> chunks: [kc][208 rows x 32 k] bf16 hi, lo ----
__global__ void pack_w(const float* __restrict__ W, int K, int nkc,
                       __bf16* __restrict__ out)
{
    const int total = nkc * 1664;            // 16B-chunks per k-chunk = 1664
    for (int g = blockIdx.x * blockDim.x + threadIdx.x; g < total;
         g += gridDim.x * blockDim.x) {
        const int kc = g / 1664;
        const int o  = g - kc * 1664;
        const int isLo = (o >= 832);
        const int o2 = isLo ? o - 832 : o;
        const int r  = o2 >> 2;              // 0..207
        const int k  = kc * 32 + (o2 & 3) * 8;
        bf16x8 v;
        if (r < HDIM && k < K) {             // K % 8 == 0
            const float* p = W + (size_t)r * K + k;
            float4 a = *(const float4*)p, b = *(const float4*)(p + 4);
            float f[8] = {a.x, a.y, a.z, a.w, b.x, b.y, b.z, b.w};
#pragma unroll
            for (int i = 0; i < 8; ++i) {
                __bf16 h = (__bf16)f[i];
                v[i] = isLo ? (__bf16)(f[i] - (float)h) : h;
            }
        } else {
#pragma unroll
            for (int i = 0; i < 8; ++i) v[i] = (__bf16)0.f;
        }
        *(bf16x8*)&out[(size_t)g * 8] = v;
    }
}

// ---- pipelined GEMM: C[m][n] = sum_k A[m][k]*W[n][k] over this block's k ----
// BM=64 (4 Mtiles). 8 waves = 2 M-groups (2 Mtiles each) x 4 N-groups
// (4/3/3/3 ntiles). One barrier/kstep. 68 KB LDS -> 2 blocks/CU.
__global__ __launch_bounds__(512, 4)
void gemm_pipe(const float* __restrict__ A, int lda, int K,
               const __bf16* __restrict__ Bpack,
               float* __restrict__ Cbase, int per_split, int ksteps)
{
    __shared__ alignas(16) __bf16 Ab[2][4096];    // [hi 2048 | lo 2048] (64x32)
    __shared__ alignas(16) __bf16 Bb[2][13312];   // [hi 6656 | lo 6656] (208x32)

    const int tid = threadIdx.x;
    const int kc0 = blockIdx.y * ksteps;
    const int m0  = blockIdx.x * BM;
    float* __restrict__ C = Cbase + (size_t)blockIdx.y * per_split;

    const int wv = tid >> 6, lane = tid & 63;
    const int r16 = lane & 15, kg = lane >> 4;
    const int mg = wv & 1, ng = wv >> 1;
    const int nt0 = ng ? 1 + ng * 3 : 0;        // 0,4,7,10
    const int ntw = ng ? 3 : 4;

    const int a_row = tid >> 3;          // 0..63
    const int a_q   = tid & 7;           // float4 column group
    const float* Arow = A + (size_t)(m0 + a_row) * lda + a_q * 4;

    f32x4 acc[2][4];
#pragma unroll
    for (int mi = 0; mi < 2; ++mi)
#pragma unroll
        for (int j = 0; j < 4; ++j) acc[mi][j] = (f32x4)0.f;

    float av[4];
    auto loadA = [&](int ks) {
        const int kb = (kc0 + ks) * 32;
        if (kb + a_q * 4 < K) {          // 4-granular, K % 4 == 0
            float4 x0 = *(const float4*)(Arow + kb);
            av[0] = x0.x; av[1] = x0.y; av[2] = x0.z; av[3] = x0.w;
        } else {
#pragma unroll
            for (int i = 0; i < 4; ++i) av[i] = 0.f;
        }
    };
    auto issueB = [&](int ks, int buf) {
        const char* src = (const char*)Bpack + (size_t)(kc0 + ks) * CHUNK_B;
        char* dst = (char*)&Bb[buf][0];
#pragma unroll
        for (int r = 0; r < 3; ++r)
            glds16(src + (r * 512 + tid) * 16, dst + (r * 512 + tid) * 16);
        if (tid < 128)
            glds16(src + (1536 + tid) * 16, dst + (1536 + tid) * 16);
    };

    loadA(0);
    issueB(0, 0);

    for (int ks = 0; ks < ksteps; ++ks) {
        const int cur = ks & 1, nxt = cur ^ 1;
        // commit A regs -> LDS hi/lo  (Ab[cur] last read in iter ks-2: safe)
        bf16x4 th, tl;
#pragma unroll
        for (int i = 0; i < 4; ++i) {
            __bf16 h = (__bf16)av[i];
            th[i] = h; tl[i] = (__bf16)(av[i] - (float)h);
        }
        *(bf16x4*)&Ab[cur][a_row * 32 + a_q * 4]        = th;
        *(bf16x4*)&Ab[cur][2048 + a_row * 32 + a_q * 4] = tl;
        __syncthreads();   // drains glds B(ks)->Bb[cur] + A writes (vmcnt+lgkm)
        if (ks + 1 < ksteps) { issueB(ks + 1, nxt); loadA(ks + 1); }

        const int ao0 = (mg * 32 + r16) * 32 + kg * 8;
        const int ao1 = ao0 + 16 * 32;
        bf16x8 ah0 = *(const bf16x8*)&Ab[cur][ao0];
        bf16x8 al0 = *(const bf16x8*)&Ab[cur][2048 + ao0];
        bf16x8 ah1 = *(const bf16x8*)&Ab[cur][ao1];
        bf16x8 al1 = *(const bf16x8*)&Ab[cur][2048 + ao1];
#pragma unroll
        for (int j = 0; j < 4; ++j) {
            if (j < ntw) {
                const int bo = ((nt0 + j) * 16 + r16) * 32 + kg * 8;
                bf16x8 bh = *(const bf16x8*)&Bb[cur][bo];
                bf16x8 bl = *(const bf16x8*)&Bb[cur][6656 + bo];
                acc[0][j] = MFMA(al0, bh, acc[0][j]);
                acc[0][j] = MFMA(ah0, bl, acc[0][j]);
                acc[0][j] = MFMA(ah0, bh, acc[0][j]);
                acc[1][j] = MFMA(al1, bh, acc[1][j]);
                acc[1][j] = MFMA(ah1, bl, acc[1][j]);
                acc[1][j] = MFMA(ah1, bh, acc[1][j]);
            }
        }
    }

    // epilogue: C/D layout col=lane&15, row=(lane>>4)*4+reg; plain stores
#pragma unroll
    for (int mi = 0; mi < 2; ++mi) {
        const int rb = m0 + mg * 32 + mi * 16 + kg * 4;
#pragma unroll
        for (int j = 0; j < 4; ++j) {
            if (j < ntw) {
                const int n = (nt0 + j) * 16 + r16;
                if (n < HDIM)
#pragma unroll
                    for (int r = 0; r < 4; ++r)
                        C[(size_t)(rb + r) * HDIM + n] = acc[mi][j][r];
            }
        }
    }
}

// ---- sum 16 k-split partials ----
__global__ void reduce_parts(const float* __restrict__ Pp, float* __restrict__ P)
{
    const int i = blockIdx.x * blockDim.x + threadIdx.x;   // float4 index
    if (i < 102400) {
        float4 s = ((const float4*)Pp)[i];
#pragma unroll
        for (int r = 1; r < 16; ++r) {
            float4 v = ((const float4*)Pp)[(size_t)r * 102400 + i];
            s.x += v.x; s.y += v.y; s.z += v.z; s.w += v.w;
        }
        ((float4*)P)[i] = s;
    }
}

__device__ __forceinline__ float fast_tanh(float x) {
    float e = __expf(-2.f * fabsf(x));
    float r = (1.f - e) / (1.f + e);
    return copysignf(r, x);
}

// ---- recurrence: 1 block/batch. thread owns 4 n x 28 k (zero-padded to 224);
// 8-way k-split reduced by shfl_xor butterfly; h[2] parity double buffer;
// ONE barrier per step. ----
__global__ __launch_bounds__(512, 1)
void rnn_rec(const float* __restrict__ pre,   // [32][64][200] (GEMM only)
             const float* __restrict__ Whh,   // [200][200]
             const float* __restrict__ bih,
             const float* __restrict__ bhh,
             float* __restrict__ Hout)        // [32][64][200]
{
    const int b   = blockIdx.x;
    const int tid = threadIdx.x;

    __shared__ float preS[64 * HDIM];          // 51.2 KB
    __shared__ alignas(16) float h[2][224];    // parity double buffer, padded
    __shared__ float bias[HDIM];

    {   // stage pre slab (coalesced)
        const float4* ps = (const float4*)(pre + (size_t)b * 64 * HDIM);
        float4* pd = (float4*)preS;
        for (int i = tid; i < 3200; i += 512) pd[i] = ps[i];
    }

    const bool act = tid < 400;
    const int g  = tid >> 3;            // n-group 0..49
    const int s  = tid & 7;             // k-slice 0..7
    const int n0 = g * 4;
    const int k0 = s * 28;              // slice stride 28 floats: conflict-free

    float w[4][28];
    if (act) {
#pragma unroll
        for (int j = 0; j < 4; ++j) {
            const float* wr = Whh + (size_t)(n0 + j) * HDIM;
#pragma unroll
            for (int i = 0; i < 28; ++i) {
                const int k = k0 + i;
                w[j][i] = (k < HDIM) ? wr[k] : 0.f;
            }
        }
    }
    if (tid < HDIM) bias[tid] = bih[tid] + bhh[tid];
    if (tid < 224) { h[0][tid] = 0.f; h[1][tid] = 0.f; }   // pads stay zero
    __syncthreads();

    for (int t = 0; t < 64; ++t) {
        const int p = t & 1;
        if (act) {
            float a0 = 0.f, a1 = 0.f, a2 = 0.f, a3 = 0.f;
#pragma unroll
            for (int i = 0; i < 7; ++i) {
                float4 hv = *(const float4*)&h[p][k0 + i * 4];
                a0 += w[0][i*4+0]*hv.x + w[0][i*4+1]*hv.y + w[0][i*4+2]*hv.z + w[0][i*4+3]*hv.w;
                a1 += w[1][i*4+0]*hv.x + w[1][i*4+1]*hv.y + w[1][i*4+2]*hv.z + w[1][i*4+3]*hv.w;
                a2 += w[2][i*4+0]*hv.x + w[2][i*4+1]*hv.y + w[2][i*4+2]*hv.z + w[2][i*4+3]*hv.w;
                a3 += w[3][i*4+0]*hv.x + w[3][i*4+1]*hv.y + w[3][i*4+2]*hv.z + w[3][i*4+3]*hv.w;
            }
            // butterfly over the 8-lane k-slice group
            a0 += __shfl_xor(a0, 1); a1 += __shfl_xor(a1, 1);
            a2 += __shfl_xor(a2, 1); a3 += __shfl_xor(a3, 1);
            a0 += __shfl_xor(a0, 2); a1 += __shfl_xor(a1, 2);
            a2 += __shfl_xor(a2, 2); a3 += __shfl_xor(a3, 2);
            a0 += __shfl_xor(a0, 4); a1 += __shfl_xor(a1, 4);
            a2 += __shfl_xor(a2, 4); a3 += __shfl_xor(a3, 4);
            if (s < 4) {                // lane s finalizes output n0+s (<200)
                const int n = n0 + s;
                const float sum = (s == 0) ? a0 : (s == 1) ? a1 : (s == 2) ? a2 : a3;
                const float v = fast_tanh(sum + preS[t * HDIM + n] + bias[n]);
                h[p ^ 1][n] = v;
                Hout[((size_t)b * 64 + t) * HDIM + n] = v;
            }
        }
        __syncthreads();   // covers h[p^1] RAW for t+1 AND h[p] WAR for t+1
    }
}

// ---- trivially-correct FC head ----
__global__ void fc_head(const float* __restrict__ Hlast_base,
                        const float* __restrict__ fcw,
                        const float* __restrict__ fcb,
                        float* __restrict__ out)
{
    const int i = threadIdx.x;
    if (i >= 64) return;
    const int b = i >> 1, cls = i & 1;
    const float* hp = Hlast_base + ((size_t)b * 64 + 63) * HDIM;
    const float* fw = fcw + cls * HDIM;
    float s = fcb[cls];
    for (int j = 0; j < HDIM; ++j) s += hp[j] * fw[j];
    out[b * 2 + cls] = s;
}

extern "C" void kernel_launch(void* const* d_in, const int* in_sizes, int n_in,
                              void* d_out, int out_size, void* d_ws, size_t ws_size,
                              hipStream_t stream) {
    const float* x     = (const float*)d_in[0];
    const float* W_ih0 = (const float*)d_in[1];
    const float* W_hh0 = (const float*)d_in[2];
    const float* b_ih0 = (const float*)d_in[3];
    const float* b_hh0 = (const float*)d_in[4];
    const float* W_ih1 = (const float*)d_in[5];
    const float* W_hh1 = (const float*)d_in[6];
    const float* b_ih1 = (const float*)d_in[7];
    const float* b_hh1 = (const float*)d_in[8];
    const float* W_ih2 = (const float*)d_in[9];
    const float* W_hh2 = (const float*)d_in[10];
    const float* b_ih2 = (const float*)d_in[11];
    const float* b_hh2 = (const float*)d_in[12];
    const float* fc_w  = (const float*)d_in[13];
    const float* fc_b  = (const float*)d_in[14];
    float* out = (float*)d_out;

    const size_t PE = (size_t)2048 * HDIM;          // 409600
    float* P     = (float*)d_ws;
    float* Hbuf  = P + PE;
    float* Hbuf2 = Hbuf + PE;
    float* Ppart = Hbuf2 + PE;                      // 16 x 409600
    __bf16* W0p  = (__bf16*)(Ppart + 16 * PE);      // 320 chunks x 13312 bf16
    __bf16* W1p  = W0p + (size_t)320 * 13312;       // 7 chunks
    __bf16* W2p  = W1p + (size_t)7 * 13312;
    // total ws: ~40.0 MB

    // ---- prologue: pack weights ----
    pack_w<<<1024, 256, 0, stream>>>(W_ih0, 10000, 320, W0p);
    pack_w<<<46, 256, 0, stream>>>(W_ih1, HDIM, 7, W1p);
    pack_w<<<46, 256, 0, stream>>>(W_ih2, HDIM, 7, W2p);

    // ---- layer 0: K=10000, 16-way k-split (20 ksteps each), partials ----
    gemm_pipe<<<dim3(32, 16), 512, 0, stream>>>(x, 10000, 10000, W0p, Ppart, (int)PE, 20);
    reduce_parts<<<400, 256, 0, stream>>>(Ppart, P);
    rnn_rec<<<32, 512, 0, stream>>>(P, W_hh0, b_ih0, b_hh0, Hbuf);

    // ---- layer 1: K=200, single split, direct store ----
    gemm_pipe<<<dim3(32, 1), 512, 0, stream>>>(Hbuf, HDIM, HDIM, W1p, P, (int)PE, 7);
    rnn_rec<<<32, 512, 0, stream>>>(P, W_hh1, b_ih1, b_hh1, Hbuf2);

    // ---- layer 2 ----
    gemm_pipe<<<dim3(32, 1), 512, 0, stream>>>(Hbuf2, HDIM, HDIM, W2p, P, (int)PE, 7);
    rnn_rec<<<32, 512, 0, stream>>>(P, W_hh2, b_ih2, b_hh2, Hbuf);

    // ---- FC head ----
    fc_head<<<1, 64, 0, stream>>>(Hbuf, fc_w, fc_b, out);
}

// Round 2
// 333.360 us; speedup vs baseline: 1.1823x; 1.1823x over previous
//
#include <hip/hip_runtime.h>
#include <hip/hip_bf16.h>

// 3-layer tanh RNN. B=32, T=64, D_IN=10000, H=200, N_CLASSES=2.
//
// R9:
//  * rec REGRESSION FIX: R8's w[4][28]=112 floats spilled (VGPR_Count=80 <
//    112 live) and the 3-round shfl_xor butterfly added ~400cyc of dependent
//    ds_bpermute latency per step. Revert to 2-barrier part[] reduce at the
//    PROVEN no-spill budget: G=100 n-groups x S=5 k-slices, w[2][40]=80
//    floats (R7-proven), part[5] (half of R7's 10-deep reduce).
//  * launch surgery 11->7: one pack_all kernel (was 3 pack_w); reduce_parts
//    folded into rec L0's preS staging (kills launch + P round-trip);
//    fc_head folded into rec L2's epilogue (h63 already in LDS).
//  * gemm: R8's BM=64 / 2-blocks-per-CU version retained unchanged (left
//    the top-5 after the occupancy fix).
//  * split-bf16 3-term everywhere: ~fp32 accuracy at bf16 MFMA rate.

typedef __bf16  bf16x8 __attribute__((ext_vector_type(8)));
typedef __bf16  bf16x4 __attribute__((ext_vector_type(4)));
typedef float   f32x4  __attribute__((ext_vector_type(4)));

#define HDIM 200
#define BM 64
#define CHUNK_B 26624   // bytes per packed k-chunk: [208x32] hi (13312) + lo
#define MFMA(a, b, c) __builtin_amdgcn_mfma_f32_16x16x32_bf16(a, b, c, 0, 0, 0)

__device__ __forceinline__ void glds16(const void* g, void* l) {
    __builtin_amdgcn_global_load_lds(
        (const __attribute__((address_space(1))) unsigned int*)g,
        (__attribute__((address_space(3))) unsigned int*)l, 16, 0, 0);
}

// ---- pack W [HDIM x K] fp32 -> chunks: [kc][208 rows x 32 k] bf16 hi, lo ----
// One launch packs all three W_ih weights (W0 dominates: 320 of 334 chunks).
__global__ void pack_all(const float* __restrict__ W0,
                         const float* __restrict__ W1,
                         const float* __restrict__ W2,
                         __bf16* __restrict__ O0,
                         __bf16* __restrict__ O1,
                         __bf16* __restrict__ O2)
{
    const int T0 = 320 * 1664, T1 = 7 * 1664, T2 = 7 * 1664;
    for (int gt = blockIdx.x * blockDim.x + threadIdx.x; gt < T0 + T1 + T2;
         gt += gridDim.x * blockDim.x) {
        const float* W; __bf16* out; int K, g;
        if (gt < T0)           { W = W0; out = O0; K = 10000; g = gt; }
        else if (gt < T0 + T1) { W = W1; out = O1; K = HDIM;  g = gt - T0; }
        else                   { W = W2; out = O2; K = HDIM;  g = gt - T0 - T1; }

        const int kc = g / 1664;
        const int o  = g - kc * 1664;
        const int isLo = (o >= 832);
        const int o2 = isLo ? o - 832 : o;
        const int r  = o2 >> 2;              // 0..207
        const int k  = kc * 32 + (o2 & 3) * 8;
        bf16x8 v;
        if (r < HDIM && k < K) {             // K % 8 == 0
            const float* p = W + (size_t)r * K + k;
            float4 a = *(const float4*)p, b = *(const float4*)(p + 4);
            float f[8] = {a.x, a.y, a.z, a.w, b.x, b.y, b.z, b.w};
#pragma unroll
            for (int i = 0; i < 8; ++i) {
                __bf16 h = (__bf16)f[i];
                v[i] = isLo ? (__bf16)(f[i] - (float)h) : h;
            }
        } else {
#pragma unroll
            for (int i = 0; i < 8; ++i) v[i] = (__bf16)0.f;
        }
        *(bf16x8*)&out[(size_t)g * 8] = v;
    }
}

// ---- pipelined GEMM: C[m][n] = sum_k A[m][k]*W[n][k] over this block's k ----
// BM=64 (4 Mtiles). 8 waves = 2 M-groups (2 Mtiles each) x 4 N-groups
// (4/3/3/3 ntiles). One barrier/kstep. 68 KB LDS -> 2 blocks/CU.
__global__ __launch_bounds__(512, 4)
void gemm_pipe(const float* __restrict__ A, int lda, int K,
               const __bf16* __restrict__ Bpack,
               float* __restrict__ Cbase, int per_split, int ksteps)
{
    __shared__ alignas(16) __bf16 Ab[2][4096];    // [hi 2048 | lo 2048] (64x32)
    __shared__ alignas(16) __bf16 Bb[2][13312];   // [hi 6656 | lo 6656] (208x32)

    const int tid = threadIdx.x;
    const int kc0 = blockIdx.y * ksteps;
    const int m0  = blockIdx.x * BM;
    float* __restrict__ C = Cbase + (size_t)blockIdx.y * per_split;

    const int wv = tid >> 6, lane = tid & 63;
    const int r16 = lane & 15, kg = lane >> 4;
    const int mg = wv & 1, ng = wv >> 1;
    const int nt0 = ng ? 1 + ng * 3 : 0;        // 0,4,7,10
    const int ntw = ng ? 3 : 4;

    const int a_row = tid >> 3;          // 0..63
    const int a_q   = tid & 7;           // float4 column group
    const float* Arow = A + (size_t)(m0 + a_row) * lda + a_q * 4;

    f32x4 acc[2][4];
#pragma unroll
    for (int mi = 0; mi < 2; ++mi)
#pragma unroll
        for (int j = 0; j < 4; ++j) acc[mi][j] = (f32x4)0.f;

    float av[4];
    auto loadA = [&](int ks) {
        const int kb = (kc0 + ks) * 32;
        if (kb + a_q * 4 < K) {          // 4-granular, K % 4 == 0
            float4 x0 = *(const float4*)(Arow + kb);
            av[0] = x0.x; av[1] = x0.y; av[2] = x0.z; av[3] = x0.w;
        } else {
#pragma unroll
            for (int i = 0; i < 4; ++i) av[i] = 0.f;
        }
    };
    auto issueB = [&](int ks, int buf) {
        const char* src = (const char*)Bpack + (size_t)(kc0 + ks) * CHUNK_B;
        char* dst = (char*)&Bb[buf][0];
#pragma unroll
        for (int r = 0; r < 3; ++r)
            glds16(src + (r * 512 + tid) * 16, dst + (r * 512 + tid) * 16);
        if (tid < 128)
            glds16(src + (1536 + tid) * 16, dst + (1536 + tid) * 16);
    };

    loadA(0);
    issueB(0, 0);

    for (int ks = 0; ks < ksteps; ++ks) {
        const int cur = ks & 1, nxt = cur ^ 1;
        // commit A regs -> LDS hi/lo  (Ab[cur] last read in iter ks-2: safe)
        bf16x4 th, tl;
#pragma unroll
        for (int i = 0; i < 4; ++i) {
            __bf16 h = (__bf16)av[i];
            th[i] = h; tl[i] = (__bf16)(av[i] - (float)h);
        }
        *(bf16x4*)&Ab[cur][a_row * 32 + a_q * 4]        = th;
        *(bf16x4*)&Ab[cur][2048 + a_row * 32 + a_q * 4] = tl;
        __syncthreads();   // drains glds B(ks)->Bb[cur] + A writes (vmcnt+lgkm)
        if (ks + 1 < ksteps) { issueB(ks + 1, nxt); loadA(ks + 1); }

        const int ao0 = (mg * 32 + r16) * 32 + kg * 8;
        const int ao1 = ao0 + 16 * 32;
        bf16x8 ah0 = *(const bf16x8*)&Ab[cur][ao0];
        bf16x8 al0 = *(const bf16x8*)&Ab[cur][2048 + ao0];
        bf16x8 ah1 = *(const bf16x8*)&Ab[cur][ao1];
        bf16x8 al1 = *(const bf16x8*)&Ab[cur][2048 + ao1];
#pragma unroll
        for (int j = 0; j < 4; ++j) {
            if (j < ntw) {
                const int bo = ((nt0 + j) * 16 + r16) * 32 + kg * 8;
                bf16x8 bh = *(const bf16x8*)&Bb[cur][bo];
                bf16x8 bl = *(const bf16x8*)&Bb[cur][6656 + bo];
                acc[0][j] = MFMA(al0, bh, acc[0][j]);
                acc[0][j] = MFMA(ah0, bl, acc[0][j]);
                acc[0][j] = MFMA(ah0, bh, acc[0][j]);
                acc[1][j] = MFMA(al1, bh, acc[1][j]);
                acc[1][j] = MFMA(ah1, bl, acc[1][j]);
                acc[1][j] = MFMA(ah1, bh, acc[1][j]);
            }
        }
    }

    // epilogue: C/D layout col=lane&15, row=(lane>>4)*4+reg; plain stores
#pragma unroll
    for (int mi = 0; mi < 2; ++mi) {
        const int rb = m0 + mg * 32 + mi * 16 + kg * 4;
#pragma unroll
        for (int j = 0; j < 4; ++j) {
            if (j < ntw) {
                const int n = (nt0 + j) * 16 + r16;
                if (n < HDIM)
#pragma unroll
                    for (int r = 0; r < 4; ++r)
                        C[(size_t)(rb + r) * HDIM + n] = acc[mi][j][r];
            }
        }
    }
}

__device__ __forceinline__ float fast_tanh(float x) {
    float e = __expf(-2.f * fabsf(x));
    float r = (1.f - e) / (1.f + e);
    return copysignf(r, x);
}

// ---- recurrence: 1 block/batch; thread owns 2 n x 40 k; w[80] in VGPRs
// (proven no-spill budget). 5-way k-split, part[] LDS reduce, 2 barriers/step.
// Prologue sums nparts k-split GEMM partials directly into preS (replaces
// reduce_parts kernel). Optional fused FC head for the last layer. ----
__global__ __launch_bounds__(512, 1)
void rnn_rec(const float* __restrict__ pre,   // [nparts][32][64][200] partials
             int nparts, int pstride,          // floats between partials
             const float* __restrict__ Whh,   // [200][200]
             const float* __restrict__ bih,
             const float* __restrict__ bhh,
             float* __restrict__ Hout,        // [32][64][200]
             const float* __restrict__ fcw,   // [2][200] or nullptr
             const float* __restrict__ fcb,
             float* __restrict__ outp)        // [32][2]
{
    const int b   = blockIdx.x;
    const int tid = threadIdx.x;

    __shared__ float preS[64 * HDIM];          // 51.2 KB
    __shared__ float h[HDIM];
    __shared__ float bias[HDIM];
    __shared__ float part[5][HDIM];            // 4 KB

    {   // stage pre slab, summing k-split partials (coalesced, 16-deep MLP)
        const float4* ps = (const float4*)(pre + (size_t)b * 64 * HDIM);
        float4* pd = (float4*)preS;
        const size_t pq = (size_t)pstride / 4;      // float4 stride
        for (int i = tid; i < 3200; i += 512) {
            float4 s = ps[i];
            for (int r = 1; r < nparts; ++r) {
                float4 v = ps[(size_t)r * pq + i];
                s.x += v.x; s.y += v.y; s.z += v.z; s.w += v.w;
            }
            pd[i] = s;
        }
    }

    const bool act = tid < 500;
    const int g  = tid / 5;             // n-group 0..99 (div by 5: setup only)
    const int s5 = tid - g * 5;         // k-slice 0..4
    const int n0 = g * 2;
    const int k0 = s5 * 40;

    float w[2][40];
    if (act) {
#pragma unroll
        for (int j = 0; j < 2; ++j) {
            const float* wr = Whh + (size_t)(n0 + j) * HDIM + k0;
#pragma unroll
            for (int i = 0; i < 10; ++i) {
                float4 v = *(const float4*)(wr + i * 4);
                w[j][i * 4 + 0] = v.x; w[j][i * 4 + 1] = v.y;
                w[j][i * 4 + 2] = v.z; w[j][i * 4 + 3] = v.w;
            }
        }
    }
    if (tid < HDIM) { bias[tid] = bih[tid] + bhh[tid]; h[tid] = 0.f; }
    __syncthreads();

    for (int t = 0; t < 64; ++t) {
        if (act) {
            float a0 = 0.f, a1 = 0.f;
#pragma unroll
            for (int i = 0; i < 10; ++i) {
                float4 hv = *(const float4*)&h[k0 + i * 4];
                a0 += w[0][i*4+0]*hv.x + w[0][i*4+1]*hv.y + w[0][i*4+2]*hv.z + w[0][i*4+3]*hv.w;
                a1 += w[1][i*4+0]*hv.x + w[1][i*4+1]*hv.y + w[1][i*4+2]*hv.z + w[1][i*4+3]*hv.w;
            }
            *(float2*)&part[s5][n0] = make_float2(a0, a1);
        }
        __syncthreads();   // part ready; h no longer read this step
        if (tid < HDIM) {
            float sum = part[0][tid] + part[1][tid] + part[2][tid]
                      + part[3][tid] + part[4][tid];
            float v = fast_tanh(sum + preS[t * HDIM + tid] + bias[tid]);
            h[tid] = v;
            Hout[((size_t)b * 64 + t) * HDIM + tid] = v;
        }
        __syncthreads();   // h ready for step t+1; part free for rewrite
    }

    // fused FC head (last layer only): h == h_63 in LDS
    if (fcw != nullptr && tid < 16) {
        const int cls = tid & 1, sl = tid >> 1;      // 8 slices of 25
        const float* fw = fcw + cls * HDIM + sl * 25;
        const float* hp = h + sl * 25;
        float sacc = 0.f;
#pragma unroll
        for (int j = 0; j < 25; ++j) sacc += hp[j] * fw[j];
        sacc += __shfl_xor(sacc, 2);
        sacc += __shfl_xor(sacc, 4);
        sacc += __shfl_xor(sacc, 8);
        if (sl == 0) outp[b * 2 + cls] = sacc + fcb[cls];
    }
}

extern "C" void kernel_launch(void* const* d_in, const int* in_sizes, int n_in,
                              void* d_out, int out_size, void* d_ws, size_t ws_size,
                              hipStream_t stream) {
    const float* x     = (const float*)d_in[0];
    const float* W_ih0 = (const float*)d_in[1];
    const float* W_hh0 = (const float*)d_in[2];
    const float* b_ih0 = (const float*)d_in[3];
    const float* b_hh0 = (const float*)d_in[4];
    const float* W_ih1 = (const float*)d_in[5];
    const float* W_hh1 = (const float*)d_in[6];
    const float* b_ih1 = (const float*)d_in[7];
    const float* b_hh1 = (const float*)d_in[8];
    const float* W_ih2 = (const float*)d_in[9];
    const float* W_hh2 = (const float*)d_in[10];
    const float* b_ih2 = (const float*)d_in[11];
    const float* b_hh2 = (const float*)d_in[12];
    const float* fc_w  = (const float*)d_in[13];
    const float* fc_b  = (const float*)d_in[14];
    float* out = (float*)d_out;

    const size_t PE = (size_t)2048 * HDIM;          // 409600
    float* P     = (float*)d_ws;
    float* Hbuf  = P + PE;
    float* Hbuf2 = Hbuf + PE;
    float* Ppart = Hbuf2 + PE;                      // 16 x 409600
    __bf16* W0p  = (__bf16*)(Ppart + 16 * PE);      // 320 chunks x 13312 bf16
    __bf16* W1p  = W0p + (size_t)320 * 13312;       // 7 chunks
    __bf16* W2p  = W1p + (size_t)7 * 13312;
    // total ws: ~40.0 MB

    // ---- prologue: pack all weights (one launch) ----
    pack_all<<<1024, 256, 0, stream>>>(W_ih0, W_ih1, W_ih2, W0p, W1p, W2p);

    // ---- layer 0: K=10000, 16-way k-split (20 ksteps each); partials are
    //      reduced inside rnn_rec's staging ----
    gemm_pipe<<<dim3(32, 16), 512, 0, stream>>>(x, 10000, 10000, W0p, Ppart, (int)PE, 20);
    rnn_rec<<<32, 512, 0, stream>>>(Ppart, 16, (int)PE, W_hh0, b_ih0, b_hh0,
                                    Hbuf, nullptr, nullptr, nullptr);

    // ---- layer 1: K=200, single split, direct store ----
    gemm_pipe<<<dim3(32, 1), 512, 0, stream>>>(Hbuf, HDIM, HDIM, W1p, P, (int)PE, 7);
    rnn_rec<<<32, 512, 0, stream>>>(P, 1, (int)PE, W_hh1, b_ih1, b_hh1,
                                    Hbuf2, nullptr, nullptr, nullptr);

    // ---- layer 2 + fused FC head ----
    gemm_pipe<<<dim3(32, 1), 512, 0, stream>>>(Hbuf2, HDIM, HDIM, W2p, P, (int)PE, 7);
    rnn_rec<<<32, 512, 0, stream>>>(P, 1, (int)PE, W_hh2, b_ih2, b_hh2,
                                    Hbuf, fc_w, fc_b, out);
}